// Round 10
// baseline (38.253 us; speedup 1.0000x reference)
//
#include <hip/hip_runtime.h>
#include <hip/hip_bf16.h>

// Problem constants (match reference)
#define BB 16384
#define DD 512
#define NCLS 90
#define KC 32
#define BUCKET 512   // max samples per class (mean 182, +24 sigma headroom)
#define PRB 180      // center-norm blocks in k_prep (2880 rows / 16 waves)
#define CH 16        // 32-sample chunk slots per class (covers n <= 512)
#define NSLOT (NCLS * CH)

typedef __attribute__((ext_vector_type(8))) short short8;   // 8 bf16 (4 VGPRs)
typedef __attribute__((ext_vector_type(4))) float fx4;      // MFMA accumulator

static __device__ __forceinline__ short f2bf(float f) {
    unsigned u = __float_as_uint(f);
    unsigned r = (u + 0x7fffu + ((u >> 16) & 1u)) >> 16;    // RNE
    return (short)r;
}

// ------- kernel 1: prep (1024 thr) = center norm (0..179) + LDS binning (180..269)
// (R9-verbatim: proven 7.3 us faster than the global-scan version)
__global__ __launch_bounds__(1024)
void k_prep(const float* __restrict__ centers, const int* __restrict__ labels,
            short* __restrict__ cni, int* __restrict__ idx, int* __restrict__ cnt) {
    __shared__ int lab[BB];       // 64 KiB: label cache for binning blocks
    __shared__ int wcnt[16];

    int t = threadIdx.x, w = t >> 6, lane = t & 63;

    if ((int)blockIdx.x < PRB) {
        // ---- normalize 16 center rows -> bf16 image (one wave per row) ----
        int row = blockIdx.x * 16 + w;                  // 0..2879
        const float4* p = (const float4*)(centers + (size_t)row * DD);
        float4 a = p[lane * 2];
        float4 b = p[lane * 2 + 1];
        float s = a.x * a.x + a.y * a.y + a.z * a.z + a.w * a.w
                + b.x * b.x + b.y * b.y + b.z * b.z + b.w * b.w;
#pragma unroll
        for (int m = 1; m < 64; m <<= 1) s += __shfl_xor(s, m, 64);
        float sc = rsqrtf(s + 1e-12f);
        short8 v;
        v[0] = f2bf(a.x * sc); v[1] = f2bf(a.y * sc);
        v[2] = f2bf(a.z * sc); v[3] = f2bf(a.w * sc);
        v[4] = f2bf(b.x * sc); v[5] = f2bf(b.y * sc);
        v[6] = f2bf(b.z * sc); v[7] = f2bf(b.w * sc);
        *(short8*)(cni + (size_t)row * DD + lane * 8) = v;
    } else {
        // ---- deterministic binning from LDS label cache, one block/class ----
        int c = blockIdx.x - PRB;
        for (int j = t; j < BB / 4; j += 1024)          // coalesced int4 load
            ((int4*)lab)[j] = ((const int4*)labels)[j];
        __syncthreads();

        int seg4 = w * (BB / 4 / 16);                   // 256 int4s per wave
        int cw = 0;
#pragma unroll
        for (int jj = 0; jj < 4; jj++) {
            int4 v = ((int4*)lab)[seg4 + jj * 64 + lane];
            cw += (v.x == c) + (v.y == c) + (v.z == c) + (v.w == c);
        }
#pragma unroll
        for (int m = 1; m < 64; m <<= 1) cw += __shfl_xor(cw, m, 64);
        if (lane == 0) wcnt[w] = cw;
        __syncthreads();
        int pos = c * BUCKET;
        for (int ww = 0; ww < w; ww++) pos += wcnt[ww];
#pragma unroll
        for (int jj = 0; jj < 4; jj++) {
            int4 v = ((int4*)lab)[seg4 + jj * 64 + lane];
            int gbase = (seg4 + jj * 64 + lane) * 4;
            {
                bool m = (v.x == c); unsigned long long k = __ballot(m);
                if (m) idx[pos + __popcll(k & ((1ull << lane) - 1ull))] = gbase + 0;
                pos += __popcll(k);
            }
            {
                bool m = (v.y == c); unsigned long long k = __ballot(m);
                if (m) idx[pos + __popcll(k & ((1ull << lane) - 1ull))] = gbase + 1;
                pos += __popcll(k);
            }
            {
                bool m = (v.z == c); unsigned long long k = __ballot(m);
                if (m) idx[pos + __popcll(k & ((1ull << lane) - 1ull))] = gbase + 2;
                pos += __popcll(k);
            }
            {
                bool m = (v.w == c); unsigned long long k = __ballot(m);
                if (m) idx[pos + __popcll(k & ((1ull << lane) - 1ull))] = gbase + 3;
                pos += __popcll(k);
            }
        }
        if (t == 0) {
            int s = 0;
#pragma unroll
            for (int i = 0; i < 16; i++) s += wcnt[i];
            cnt[c] = s;
        }
    }
}

// ------- kernel 2: main — one 32-sample chunk per 128-thread block -----------
// No c_lds (B register-direct from bf16 image: R6/R8-validated), in-register
// softmax (R5-validated), ONE barrier per block, 32.2 KiB LDS -> 4 blocks/CU.
__global__ __launch_bounds__(128, 4)
void k_main(const float* __restrict__ x,
            const short* __restrict__ cni,
            const int* __restrict__ cnt,
            const int* __restrict__ idx,
            float* __restrict__ partials) {
    __shared__ __align__(16) short x_lds[32 * DD];   // 32 KiB, XOR-swizzled
    __shared__ float nrm_lds[32];
    __shared__ float red[2];

    int slot = blockIdx.x;
    int c = slot >> 4, ch = slot & 15;
    int n = cnt[c];
    int base = ch << 5;
    int t = threadIdx.x;
    if (base >= n) {                                 // inactive slot
        if (t == 0) partials[slot] = 0.f;
        return;
    }

    // ---- stage 32 gathered x rows: 4 threads/row, norms in-flight ----
    int row = t >> 2, l4 = t & 3;
    int i = base + row; if (i > n - 1) i = n - 1;    // clamped gather
    int g = idx[c * BUCKET + i];
    const float4* xrow = (const float4*)(x + (size_t)g * DD);
    float nrm = 0.f;
#pragma unroll
    for (int j = 0; j < 16; j++) {
        int cc = l4 + 4 * j;                          // 16B bf16 chunk 0..63
        float4 a = xrow[cc * 2], b = xrow[cc * 2 + 1];
        nrm += a.x * a.x + a.y * a.y + a.z * a.z + a.w * a.w
             + b.x * b.x + b.y * b.y + b.z * b.z + b.w * b.w;
        short8 v;
        v[0] = f2bf(a.x); v[1] = f2bf(a.y); v[2] = f2bf(a.z); v[3] = f2bf(a.w);
        v[4] = f2bf(b.x); v[5] = f2bf(b.y); v[6] = f2bf(b.z); v[7] = f2bf(b.w);
        *(short8*)&x_lds[row * DD + ((cc ^ (row & 7)) << 3)] = v;
    }
    nrm += __shfl_xor(nrm, 1, 64);
    nrm += __shfl_xor(nrm, 2, 64);
    if (l4 == 0) nrm_lds[row] = nrm;
    __syncthreads();                                  // the ONLY barrier

    // ---- MFMA: wave w = samples w*16..+15 vs ALL 32 centers (two halves) ----
    int w = t >> 6, lane = t & 63;
    int r = lane & 15, g4 = lane >> 4;
    int arow = w * 16 + r;
    const short8* c0 = (const short8*)(cni + ((size_t)(c * KC) + r) * DD);
    const short8* c1 = (const short8*)(cni + ((size_t)(c * KC) + 16 + r) * DD);
    fx4 acc0 = {0.f, 0.f, 0.f, 0.f};
    fx4 acc1 = {0.f, 0.f, 0.f, 0.f};
#pragma unroll
    for (int ks = 0; ks < 16; ks++) {
        int c16 = ks * 4 + g4;                        // this lane's 8-elem chunk
        short8 av = *(const short8*)&x_lds[arow * DD + ((c16 ^ (arow & 7)) << 3)];
        acc0 = __builtin_amdgcn_mfma_f32_16x16x32_bf16(av, c0[c16], acc0, 0, 0, 0);
        acc1 = __builtin_amdgcn_mfma_f32_16x16x32_bf16(av, c1[c16], acc1, 0, 0, 0);
    }

    // ---- in-register softmax: D row=(g4*4+j)=sample, col=lane&15=center ----
    float loss = 0.f;
#pragma unroll
    for (int j = 0; j < 4; j++) {
        int smp = w * 16 + (g4 << 2) + j;             // sample within chunk
        float xv = rsqrtf(nrm_lds[smp] + 1e-12f);
        float s0 = acc0[j] * xv;                      // center  lane&15
        float s1 = acc1[j] * xv;                      // center  16+(lane&15)
        float mx = fmaxf(s0, s1);
#pragma unroll
        for (int m = 1; m < 16; m <<= 1) mx = fmaxf(mx, __shfl_xor(mx, m, 64));
        float e0 = expf(s0 - mx), e1 = expf(s1 - mx);
        float Z = e0 + e1;
        float num = e0 * (1.f - s0) + e1 * (1.f - s1);
#pragma unroll
        for (int m = 1; m < 16; m <<= 1) {
            Z   += __shfl_xor(Z, m, 64);
            num += __shfl_xor(num, m, 64);
        }
        if (r == 0 && base + smp < n) loss += num / Z;
    }

    // ---- block partial (fixed order) ----
#pragma unroll
    for (int m = 1; m < 64; m <<= 1) loss += __shfl_xor(loss, m, 64);
    if (lane == 0) red[w] = loss;
    __syncthreads();
    if (t == 0) partials[slot] = red[0] + red[1];
}

// ------- kernel 3: deterministic final mean over 1440 slot partials ----------
__global__ void k_final(const float* __restrict__ partials, float* __restrict__ out) {
    __shared__ float red[256];
    int t = threadIdx.x;
    float s = 0.f;
    for (int i = t; i < NSLOT; i += 256) s += partials[i];
    red[t] = s;
    __syncthreads();
    for (int h = 128; h > 0; h >>= 1) {
        if (t < h) red[t] += red[t + h];
        __syncthreads();
    }
    if (t == 0) out[0] = red[0] * (1.0f / (float)BB);
}

extern "C" void kernel_launch(void* const* d_in, const int* in_sizes, int n_in,
                              void* d_out, int out_size, void* d_ws, size_t ws_size,
                              hipStream_t stream) {
    const float* x       = (const float*)d_in[0];
    const int*   labels  = (const int*)d_in[1];
    const float* centers = (const float*)d_in[2];
    float* out = (float*)d_out;

    char* ws = (char*)d_ws;
    short* cni      = (short*)(ws + 0);             // 2880*512 bf16 = 2,949,120 B
    int*   idx      = (int*)(ws + 3145728);         // 90*512 ints   =   184,320 B
    int*   cnt      = (int*)(ws + 3407872);         // 90 ints
    float* partials = (float*)(ws + 3473408);       // 1440 floats (all written)

    k_prep<<<PRB + NCLS, 1024, 0, stream>>>(centers, labels, cni, idx, cnt);
    k_main<<<NSLOT, 128, 0, stream>>>(x, cni, cnt, idx, partials);
    k_final<<<1, 256, 0, stream>>>(partials, out);
}

// Round 11
// 29.324 us; speedup vs baseline: 1.3045x; 1.3045x over previous
//
#include <hip/hip_runtime.h>
#include <hip/hip_bf16.h>

// Problem constants (match reference)
#define BB 16384
#define DD 512
#define NCLS 90
#define KC 32
#define BUCKET 512           // max samples per class (mean 182, +24 sigma headroom)
#define MAGIC 0x7f3a9c51u    // per-class "binning done" flag value

typedef __attribute__((ext_vector_type(8))) short short8;   // 8 bf16 (4 VGPRs)
typedef __attribute__((ext_vector_type(4))) float fx4;      // MFMA accumulator

// pack 8 f32 -> 8 bf16 via v_cvt_pk_bf16_f32 (RNE), optional scale
static __device__ __forceinline__ short8 pack8s(float sc, float4 a, float4 b) {
    union { __hip_bfloat162 h[4]; short8 s; } u;
    u.h[0] = __float22bfloat162_rn(make_float2(a.x * sc, a.y * sc));
    u.h[1] = __float22bfloat162_rn(make_float2(a.z * sc, a.w * sc));
    u.h[2] = __float22bfloat162_rn(make_float2(b.x * sc, b.y * sc));
    u.h[3] = __float22bfloat162_rn(make_float2(b.z * sc, b.w * sc));
    return u.s;
}
static __device__ __forceinline__ short8 pack8(float4 a, float4 b) {
    union { __hip_bfloat162 h[4]; short8 s; } u;
    u.h[0] = __float22bfloat162_rn(make_float2(a.x, a.y));
    u.h[1] = __float22bfloat162_rn(make_float2(a.z, a.w));
    u.h[2] = __float22bfloat162_rn(make_float2(b.x, b.y));
    u.h[3] = __float22bfloat162_rn(make_float2(b.z, b.w));
    return u.s;
}

// ---- fused kernel: per-class binning (p==0 blocks) + in-block center norm ---
// ---- + producer-consumer flag + R9-proven MFMA/softmax chunk loop ----------
// grid = 720. Blocks 0..89: (c=b, p=0) bin class c first (binners co-resident
// from dispatch 0 -> no deadlock). Blocks 90..719: (c,p>=1) workers.
__global__ __launch_bounds__(256, 2)
void k_main(const float* __restrict__ x,
            const float* __restrict__ centers,
            const int* __restrict__ labels,
            int* __restrict__ idx,
            int* __restrict__ cnt,
            unsigned int* __restrict__ flag,
            float* __restrict__ partials) {
    __shared__ __align__(16) char u_lds[64 * 1024];  // lab[16K int] | c_lds+x_lds
    __shared__ float S_lds[32][33];
    __shared__ float xinv[32];
    __shared__ float red[256];
    __shared__ int wcnt[4];

    int*   lab   = (int*)u_lds;                      // binning phase only
    short* c_lds = (short*)u_lds;                    // 32 KiB bf16, XOR-swizzled
    short* x_lds = (short*)(u_lds + 32768);          // 32 KiB bf16, XOR-swizzled

    int b = blockIdx.x;
    int c, p;
    if (b < NCLS) { c = b; p = 0; }
    else { c = (b - NCLS) / 7; p = 1 + (b - NCLS) % 7; }
    int t = threadIdx.x, w = t >> 6, lane = t & 63;

    if (p == 0) {
        // ---- bin class c: labels -> LDS, count, ballot-compaction emit ----
        for (int j = t; j < BB / 4; j += 256)        // coalesced int4 load
            ((int4*)lab)[j] = ((const int4*)labels)[j];
        __syncthreads();
        int seg4 = w * (BB / 4 / 4);                 // 1024 int4 per wave
        int cw = 0;
#pragma unroll
        for (int jj = 0; jj < 16; jj++) {
            int4 v = ((int4*)lab)[seg4 + jj * 64 + lane];
            cw += (v.x == c) + (v.y == c) + (v.z == c) + (v.w == c);
        }
#pragma unroll
        for (int m = 1; m < 64; m <<= 1) cw += __shfl_xor(cw, m, 64);
        if (lane == 0) wcnt[w] = cw;
        __syncthreads();
        int n0 = wcnt[0] + wcnt[1] + wcnt[2] + wcnt[3];
        int pos = c * BUCKET;
        for (int ww = 0; ww < w; ww++) pos += wcnt[ww];
#pragma unroll
        for (int jj = 0; jj < 16; jj++) {
            int4 v = ((int4*)lab)[seg4 + jj * 64 + lane];
            int gbase = (seg4 + jj * 64 + lane) * 4;
            { bool m = (v.x == c); unsigned long long k = __ballot(m);
              if (m) idx[pos + __popcll(k & ((1ull << lane) - 1ull))] = gbase;     pos += __popcll(k); }
            { bool m = (v.y == c); unsigned long long k = __ballot(m);
              if (m) idx[pos + __popcll(k & ((1ull << lane) - 1ull))] = gbase + 1; pos += __popcll(k); }
            { bool m = (v.z == c); unsigned long long k = __ballot(m);
              if (m) idx[pos + __popcll(k & ((1ull << lane) - 1ull))] = gbase + 2; pos += __popcll(k); }
            { bool m = (v.w == c); unsigned long long k = __ballot(m);
              if (m) idx[pos + __popcll(k & ((1ull << lane) - 1ull))] = gbase + 3; pos += __popcll(k); }
        }
        // zero-fill bucket tail -> unclamped gathers are safe
        for (int j = n0 + t; j < BUCKET; j += 256) idx[c * BUCKET + j] = 0;
        __syncthreads();                             // drain all waves' stores + last lab reads
        if (t == 0) {
            cnt[c] = n0;
            __hip_atomic_store(&flag[c], MAGIC, __ATOMIC_RELEASE, __HIP_MEMORY_SCOPE_AGENT);
        }
    }

    // ---- normalize this class's 32 center rows into c_lds (all blocks) ----
    {
        int row8 = t >> 3, l8 = t & 7;               // 8 threads per center row
        const float4* csrc = (const float4*)(centers + ((size_t)c * KC + row8) * DD);
        float s = 0.f;
#pragma unroll
        for (int jj = 0; jj < 8; jj++) {
            float4 a = csrc[(l8 + 8 * jj) * 2], b4 = csrc[(l8 + 8 * jj) * 2 + 1];
            s += a.x * a.x + a.y * a.y + a.z * a.z + a.w * a.w
               + b4.x * b4.x + b4.y * b4.y + b4.z * b4.z + b4.w * b4.w;
        }
#pragma unroll
        for (int m = 1; m < 8; m <<= 1) s += __shfl_xor(s, m, 64);
        float sc = rsqrtf(s + 1e-12f);
#pragma unroll
        for (int jj = 0; jj < 8; jj++) {             // second pass: L1 re-hit
            int c16 = l8 + 8 * jj;
            float4 a = csrc[c16 * 2], b4 = csrc[c16 * 2 + 1];
            *(short8*)&c_lds[row8 * DD + ((c16 ^ (row8 & 7)) << 3)] = pack8s(sc, a, b4);
        }
    }

    // ---- workers wait for this class's binning (overlapped with norm above) --
    if (p != 0 && t == 0) {
        while (__hip_atomic_load(&flag[c], __ATOMIC_ACQUIRE, __HIP_MEMORY_SCOPE_AGENT) != MAGIC)
            __builtin_amdgcn_s_sleep(2);
    }
    __syncthreads();                                 // c_lds ready + flag acquired

    int n = cnt[c];
    int nch = (n + 31) >> 5;
    float loss_acc = 0.f;

    if (p < nch) {
        int base = c * BUCKET;
        int mrow = ((w & 1) << 4) + (lane & 15);
        int nrow = ((w >> 1) << 4) + (lane & 15);
        int row8 = t >> 3, l8 = t & 7;               // 8 threads per sample row

        for (int ch = p; ch < nch; ch += 8) {
            int off = ch << 5;
            int rem = n - off;                       // > 0

            // ---- gather raw f32 x row (unclamped: tail idx = 0), norm in-flight
            {
                int g = idx[base + off + row8];
                const float4* src = (const float4*)(x + (size_t)g * DD);
                float nrm = 0.f;
#pragma unroll
                for (int jj = 0; jj < 8; jj++) {
                    int cc = l8 + 8 * jj;            // 16B bf16 chunk 0..63
                    float4 a = src[cc * 2], b4 = src[cc * 2 + 1];
                    nrm += a.x * a.x + a.y * a.y + a.z * a.z + a.w * a.w
                         + b4.x * b4.x + b4.y * b4.y + b4.z * b4.z + b4.w * b4.w;
                    *(short8*)&x_lds[row8 * DD + ((cc ^ (row8 & 7)) << 3)] = pack8(a, b4);
                }
#pragma unroll
                for (int m = 1; m < 8; m <<= 1) nrm += __shfl_xor(nrm, m, 64);
                if (l8 == 0) xinv[row8] = rsqrtf(nrm + 1e-12f);
            }
            __syncthreads();

            // ---- MFMA: S[32 samples][32 k] in 4 wave-quadrants ----
            fx4 acc = {0.f, 0.f, 0.f, 0.f};
#pragma unroll
            for (int ks = 0; ks < 16; ks++) {
                int c16a = ks * 4 + (lane >> 4);
                short8 av = *(const short8*)&x_lds[mrow * DD + ((c16a ^ (mrow & 7)) << 3)];
                short8 bv = *(const short8*)&c_lds[nrow * DD + ((c16a ^ (nrow & 7)) << 3)];
                acc = __builtin_amdgcn_mfma_f32_16x16x32_bf16(av, bv, acc, 0, 0, 0);
            }
#pragma unroll
            for (int j = 0; j < 4; j++) {
                int r = ((w & 1) << 4) + ((lane >> 4) << 2) + j;   // C/D row
                int col = ((w >> 1) << 4) + (lane & 15);           // C/D col
                S_lds[r][col] = acc[j];
            }
            __syncthreads();

            // ---- softmax over K=32 + per-sample loss; 8 threads per row ----
            {
                float xv = xinv[row8];
                int q4 = l8 << 2;
                float s0 = S_lds[row8][q4 + 0] * xv;
                float s1 = S_lds[row8][q4 + 1] * xv;
                float s2 = S_lds[row8][q4 + 2] * xv;
                float s3 = S_lds[row8][q4 + 3] * xv;
                float mx = fmaxf(fmaxf(s0, s1), fmaxf(s2, s3));
#pragma unroll
                for (int m = 1; m < 8; m <<= 1) mx = fmaxf(mx, __shfl_xor(mx, m, 64));
                float e0 = expf(s0 - mx), e1 = expf(s1 - mx);
                float e2 = expf(s2 - mx), e3 = expf(s3 - mx);
                float Z = e0 + e1 + e2 + e3;
                float num = e0 * (1.f - s0) + e1 * (1.f - s1)
                          + e2 * (1.f - s2) + e3 * (1.f - s3);
#pragma unroll
                for (int m = 1; m < 8; m <<= 1) {
                    Z += __shfl_xor(Z, m, 64);
                    num += __shfl_xor(num, m, 64);
                }
                if (l8 == 0 && row8 < rem) loss_acc += num / Z;
            }
            __syncthreads();   // protect x_lds/S_lds before next chunk
        }
    }

    // ---- per-block fixed-order partial reduction (all 720 blocks write) ----
    red[t] = loss_acc;
    __syncthreads();
    for (int h = 128; h > 0; h >>= 1) {
        if (t < h) red[t] += red[t + h];
        __syncthreads();
    }
    if (t == 0) partials[b] = red[0];
}

// ------- kernel 2: deterministic final mean over 720 block partials ----------
__global__ void k_final(const float* __restrict__ partials, float* __restrict__ out) {
    __shared__ float red[256];
    int t = threadIdx.x;
    float s = 0.f;
    for (int i = t; i < NCLS * 8; i += 256) s += partials[i];
    red[t] = s;
    __syncthreads();
    for (int h = 128; h > 0; h >>= 1) {
        if (t < h) red[t] += red[t + h];
        __syncthreads();
    }
    if (t == 0) out[0] = red[0] * (1.0f / (float)BB);
}

extern "C" void kernel_launch(void* const* d_in, const int* in_sizes, int n_in,
                              void* d_out, int out_size, void* d_ws, size_t ws_size,
                              hipStream_t stream) {
    const float* x       = (const float*)d_in[0];
    const int*   labels  = (const int*)d_in[1];
    const float* centers = (const float*)d_in[2];
    float* out = (float*)d_out;

    char* ws = (char*)d_ws;
    int*          idx      = (int*)(ws + 0);        // 90*512 ints = 184,320 B
    int*          cnt      = (int*)(ws + 184320);   // 90 ints
    unsigned int* flag     = (unsigned int*)(ws + 184832); // 90 words
    float*        partials = (float*)(ws + 196608); // 720 floats (all written)

    k_main<<<NCLS * 8, 256, 0, stream>>>(x, centers, labels, idx, cnt, flag, partials);
    k_final<<<1, 256, 0, stream>>>(partials, out);
}